// Round 10
// baseline (808.659 us; speedup 1.0000x reference)
//
#include <hip/hip_runtime.h>
#include <hip/hip_bf16.h>

// Problem constants (DecoderRNN): B=64, S=64, IMG_F=2048, EMB=HID=512, VOCAB=32000
#define B_    64
#define S_    64
#define T_    63      // S-1
#define IMGF  2048
#define EMB   512
#define HID   512
#define VOCAB 32000
#define MROWS 4032    // B_*T_
#define MPAD  4096    // padded to multiple of 128

typedef __bf16 bf16;
typedef __bf16 bf16x8 __attribute__((ext_vector_type(8)));
typedef float  f32x4  __attribute__((ext_vector_type(4)));

__device__ __forceinline__ void gload_lds16(const void* g, void* l) {
  __builtin_amdgcn_global_load_lds(
      (const __attribute__((address_space(1))) unsigned int*)g,
      (__attribute__((address_space(3))) unsigned int*)l, 16, 0, 0);
}

// lgkm-only barrier: orders LDS reads/writes across waves WITHOUT draining
// outstanding global (vmcnt) ops.
#define LGKM_BARRIER() asm volatile("s_waitcnt lgkmcnt(0)\n\ts_barrier" ::: "memory")

// ---------------------------------------------------------------------------
// Tiled transpose f32[K][N] -> bf16[N][K]  (64x64 tiles via LDS)
// ---------------------------------------------------------------------------
__global__ __launch_bounds__(256) void transpose_w(
    const float* __restrict__ W, bf16* __restrict__ WT, int K, int N)
{
  __shared__ float tile[64][65];
  const int tx = threadIdx.x & 63, ty = threadIdx.x >> 6;
  const int n0 = blockIdx.x * 64, k0 = blockIdx.y * 64;
  #pragma unroll
  for (int r = ty; r < 64; r += 4)
    tile[r][tx] = W[(size_t)(k0 + r) * N + n0 + tx];
  __syncthreads();
  #pragma unroll
  for (int r = ty; r < 64; r += 4)
    WT[(size_t)(n0 + r) * K + k0 + tx] = (bf16)tile[tx][r];
}

// ---------------------------------------------------------------------------
// Embedding gather: X[r][e] = embed_W[captions[b, t]][e], r = b*63+t, bf16 out
// ---------------------------------------------------------------------------
__global__ __launch_bounds__(256) void embed_gather(
    const float* __restrict__ embW, const int* __restrict__ captions,
    bf16* __restrict__ X)
{
  const int r = blockIdx.x;
  const int tid = threadIdx.x;
  if (r < MROWS) {
    const int b = r / T_, t = r % T_;            // t in [0,62]
    const int idx = captions[b * S_ + t];
    float2 v = ((const float2*)(embW + (size_t)idx * EMB))[tid];
    X[(size_t)r * EMB + 2 * tid]     = (bf16)v.x;
    X[(size_t)r * EMB + 2 * tid + 1] = (bf16)v.y;
  } else {
    X[(size_t)r * EMB + 2 * tid]     = (bf16)0.f;
    X[(size_t)r * EMB + 2 * tid + 1] = (bf16)0.f;
  }
}

// ---------------------------------------------------------------------------
// img -> bf16, padded to 128 rows
// ---------------------------------------------------------------------------
__global__ __launch_bounds__(256) void img_to_bf16(
    const float* __restrict__ img, bf16* __restrict__ imgB)
{
  const int r = blockIdx.x;          // 0..127
  const int tid = threadIdx.x;
  #pragma unroll
  for (int j = 0; j < 8; j++) {
    const int c = tid + j * 256;     // 0..2047
    const float v = (r < B_) ? img[(size_t)r * IMGF + c] : 0.f;
    imgB[(size_t)r * IMGF + c] = (bf16)v;
  }
}

// ---------------------------------------------------------------------------
// bf16 MFMA GEMM, 128x128 tile, 2-phase (used for the small pre/pimg GEMMs)
// ---------------------------------------------------------------------------
__global__ __launch_bounds__(256) void gemm_bt(
    const bf16* __restrict__ A, const bf16* __restrict__ BT,
    const float* __restrict__ bias, float* __restrict__ C,
    int Mvalid, int N, int K)
{
  __shared__ __align__(16) bf16 As[2][128 * 32];
  __shared__ __align__(16) bf16 Bs[2][128 * 32];
  const int tid  = threadIdx.x;
  const int wave = tid >> 6, lane = tid & 63;
  const int wm = wave >> 1, wn = wave & 1;
  const int bm = blockIdx.x, bn = blockIdx.y;
  const int lg = lane >> 4, lr = lane & 15;

  f32x4 acc[4][4];
  #pragma unroll
  for (int m = 0; m < 4; m++)
    #pragma unroll
    for (int n = 0; n < 4; n++) acc[m][n] = (f32x4){0.f, 0.f, 0.f, 0.f};

  const bf16* Abase = A  + (size_t)bm * 128 * K;
  const bf16* Bbase = BT + (size_t)bn * 128 * K;

  const int c0 = wave * 64 + lane;
  const int r0 = c0 >> 2,  sl0 = (c0 & 3) ^ ((r0 >> 1) & 3);
  const int c1 = 256 + c0;
  const int r1 = c1 >> 2,  sl1 = (c1 & 3) ^ ((r1 >> 1) & 3);

  const int NT = K >> 5;

#define STAGE_TILE(buf, kt)                                                   \
  do {                                                                        \
    gload_lds16(Abase + (size_t)r0 * K + (kt) + sl0 * 8,                      \
                &As[buf][(wave * 64) * 8]);                                   \
    gload_lds16(Abase + (size_t)r1 * K + (kt) + sl1 * 8,                      \
                &As[buf][(256 + wave * 64) * 8]);                             \
    gload_lds16(Bbase + (size_t)r0 * K + (kt) + sl0 * 8,                      \
                &Bs[buf][(wave * 64) * 8]);                                   \
    gload_lds16(Bbase + (size_t)r1 * K + (kt) + sl1 * 8,                      \
                &Bs[buf][(256 + wave * 64) * 8]);                             \
  } while (0)

  STAGE_TILE(0, 0);
  int cur = 0;
  for (int it = 0; it < NT; ++it) {
    __syncthreads();
    if (it + 1 < NT) STAGE_TILE(cur ^ 1, (it + 1) * 32);

    bf16x8 af[4], bfr[4];
    #pragma unroll
    for (int m = 0; m < 4; m++) {
      const int r = wm * 64 + m * 16 + lr;
      const int sp = lg ^ ((r >> 1) & 3);
      af[m] = *(const bf16x8*)&As[cur][r * 32 + sp * 8];
    }
    #pragma unroll
    for (int n = 0; n < 4; n++) {
      const int r = wn * 64 + n * 16 + lr;
      const int sp = lg ^ ((r >> 1) & 3);
      bfr[n] = *(const bf16x8*)&Bs[cur][r * 32 + sp * 8];
    }
    #pragma unroll
    for (int m = 0; m < 4; m++)
      #pragma unroll
      for (int n = 0; n < 4; n++)
        acc[m][n] = __builtin_amdgcn_mfma_f32_16x16x32_bf16(af[m], bfr[n], acc[m][n], 0, 0, 0);
    cur ^= 1;
  }
#undef STAGE_TILE

  const int row0 = bm * 128 + wm * 64 + (lane >> 4) * 4;
  const int col0 = bn * 128 + wn * 64 + lr;
  #pragma unroll
  for (int m = 0; m < 4; m++) {
    #pragma unroll
    for (int n = 0; n < 4; n++) {
      const int col = col0 + n * 16;
      const float bv = bias[col];
      #pragma unroll
      for (int q = 0; q < 4; q++) {
        const int row = row0 + m * 16 + q;
        if (row < Mvalid) C[(size_t)row * N + col] = acc[m][n][q] + bv;
      }
    }
  }
}

// ---------------------------------------------------------------------------
// bf16 MFMA GEMM, 256x256 tile, BK=32, 4-buffer counted-vmcnt pipeline
// (sync structure validated in R9). Swizzle FIXED to the proven mapping:
// f(r) = (r>>1)&3  (R9's f(r)=r&3 caused 12.3M bank conflicts — only 4 of 8
// (parity,slot) bank-group combos were used; (r>>1)&3 covers all 8 per 8
// consecutive rows, measured 0 conflicts on the 128^2 kernel).
// ---------------------------------------------------------------------------
__global__ __launch_bounds__(512, 1) void gemm_bt256(
    const bf16* __restrict__ A, const bf16* __restrict__ BT,
    const float* __restrict__ bias, float* __restrict__ C,
    int Mvalid, int N, int K)
{
  __shared__ __align__(16) bf16 sm[4][2][256 * 32];   // [buf][A/B][(r*4+slot)*8]
  const int tid  = threadIdx.x;
  const int wave = tid >> 6, lane = tid & 63;
  const int wm = wave >> 2, wn = wave & 3;
  const int bm = blockIdx.x, bn = blockIdx.y;
  const int lg = lane >> 4, lr = lane & 15;

  f32x4 acc[8][4];
  #pragma unroll
  for (int m = 0; m < 8; m++)
    #pragma unroll
    for (int n = 0; n < 4; n++) acc[m][n] = (f32x4){0.f, 0.f, 0.f, 0.f};

  const bf16* Abase = A  + (size_t)bm * 256 * K;
  const bf16* Bbase = BT + (size_t)bn * 256 * K;

  // staging: 1024 16B-chunks per operand (256 rows x 4); 2 per thread/operand
  const int ca0 = tid,        ra0 = ca0 >> 2, sa0 = (ca0 & 3) ^ ((ra0 >> 1) & 3);
  const int ca1 = tid + 512,  ra1 = ca1 >> 2, sa1 = (ca1 & 3) ^ ((ra1 >> 1) & 3);
  const int ldsb0 = (wave * 64) * 8;          // wave-uniform LDS bases
  const int ldsb1 = (512 + wave * 64) * 8;

#define STAGE256(buf, kt)                                                     \
  do {                                                                        \
    gload_lds16(Abase + (size_t)ra0 * K + (kt) + sa0 * 8, &sm[buf][0][ldsb0]);\
    gload_lds16(Abase + (size_t)ra1 * K + (kt) + sa1 * 8, &sm[buf][0][ldsb1]);\
    gload_lds16(Bbase + (size_t)ra0 * K + (kt) + sa0 * 8, &sm[buf][1][ldsb0]);\
    gload_lds16(Bbase + (size_t)ra1 * K + (kt) + sa1 * 8, &sm[buf][1][ldsb1]);\
  } while (0)

  const int NT = K >> 5;                      // 16 for K=512
  STAGE256(0, 0);
  STAGE256(1, 32);
  STAGE256(2, 64);

  #pragma unroll 1
  for (int it = 0; it < NT; ++it) {
    // -- readiness: my buf[it] loads done (counted), then collective barrier
    const int newer = (NT - 1 - it) > 2 ? 2 : (NT - 1 - it);
    switch (newer) {
      case 2:  asm volatile("s_waitcnt vmcnt(8)\n\ts_barrier" ::: "memory"); break;
      case 1:  asm volatile("s_waitcnt vmcnt(4)\n\ts_barrier" ::: "memory"); break;
      default: asm volatile("s_waitcnt vmcnt(0)\n\ts_barrier" ::: "memory"); break;
    }

    const bf16* As_ = sm[it & 3][0];
    const bf16* Bs_ = sm[it & 3][1];
    bf16x8 af[8], bfr[4];
    #pragma unroll
    for (int m = 0; m < 8; m++) {
      const int r = wm * 128 + m * 16 + lr;
      const int sp = lg ^ ((r >> 1) & 3);
      af[m] = *(const bf16x8*)&As_[(r * 4 + sp) * 8];
    }
    #pragma unroll
    for (int n = 0; n < 4; n++) {
      const int r = wn * 64 + n * 16 + lr;
      const int sp = lg ^ ((r >> 1) & 3);
      bfr[n] = *(const bf16x8*)&Bs_[(r * 4 + sp) * 8];
    }
    #pragma unroll
    for (int m = 0; m < 8; m++)
      #pragma unroll
      for (int n = 0; n < 4; n++)
        acc[m][n] = __builtin_amdgcn_mfma_f32_16x16x32_bf16(af[m], bfr[n], acc[m][n], 0, 0, 0);

    // -- all waves finished READING buf[it]; now safe to overwrite buf[it-1]
    LGKM_BARRIER();
    if (it + 3 < NT) STAGE256((it + 3) & 3, (it + 3) * 32);
  }
#undef STAGE256

  const int row0 = bm * 256 + wm * 128 + lg * 4;
  const int col0 = bn * 256 + wn * 64 + lr;
  #pragma unroll
  for (int m = 0; m < 8; m++) {
    #pragma unroll
    for (int n = 0; n < 4; n++) {
      const int col = col0 + n * 16;
      const float bv = bias[col];
      #pragma unroll
      for (int q = 0; q < 4; q++) {
        const int row = row0 + m * 16 + q;
        if (row < Mvalid) C[(size_t)row * N + col] = acc[m][n][q] + bv;
      }
    }
  }
}

// ---------------------------------------------------------------------------
// Persistent RNN, 8-wave. VGPR-pressure reduction vs R7-R9:
//   FREG 48->47 (188 VGPR of Wh frags), FLDS 17 (LDS 136 KB + 16 KB h =
//   155,648 B, the size proven to launch in R4/R5);
//   pre loads moved INTO the epilogue (16 floats no longer live across the
//   whole MFMA loop). Peak reg demand ~235 < 256 cap -> no spill.
// ---------------------------------------------------------------------------
#define FREG 47
#define FLDS 17   // 64 - FREG
__global__ __launch_bounds__(512, 1) void rnn_reg8(
    const float* __restrict__ pre, const bf16* __restrict__ WhT,
    const float* __restrict__ bh, const float* __restrict__ pimg,
    bf16* __restrict__ hs)
{
  const int bg  = blockIdx.x;          // batch group 0..3
  const int tid = threadIdx.x;
  const int wave = tid >> 6, lane = tid & 63;
  const int lg = lane >> 4, lr = lane & 15;
  const int gb0 = bg * 16;             // first batch of block
  const int wc0 = wave * 64;           // first col of wave

  __shared__ __align__(16) bf16 hsh[16 * 512];              // 16 KB
  __shared__ __align__(16) bf16 bls[8 * FLDS * 64 * 8];     // 136 KB

  bf16x8 bw[FREG];
  #pragma unroll
  for (int f = 0; f < 64; f++) {
    const int n = f >> 4, kf = f & 15;
    const bf16x8 v = *(const bf16x8*)(WhT + (size_t)(wc0 + n * 16 + lr) * 512
                                          + kf * 32 + lg * 8);
    if (f < FREG) bw[f] = v;
    else *(bf16x8*)&bls[((wave * FLDS + (f - FREG)) * 64 + lane) * 8] = v;
  }

  *(f32x4*)&hsh[tid * 16]     = (f32x4){0.f, 0.f, 0.f, 0.f};
  *(f32x4*)&hsh[tid * 16 + 8] = (f32x4){0.f, 0.f, 0.f, 0.f};

  float bhv[4];
  #pragma unroll
  for (int n = 0; n < 4; n++) bhv[n] = bh[wc0 + n * 16 + lr];
  const float* preb = pre + ((size_t)(gb0 + lg * 4) * T_) * 512 + wc0 + lr;

  __syncthreads();

  #pragma unroll 1
  for (int t = 0; t < T_; t++) {
    f32x4 acc[4];
    #pragma unroll
    for (int n = 0; n < 4; n++) acc[n] = (f32x4){0.f, 0.f, 0.f, 0.f};

    #pragma unroll
    for (int kf = 0; kf < 16; kf++) {
      const int c = (kf * 4 + lg) ^ (lr & 7);
      const bf16x8 a = *(const bf16x8*)&hsh[(lr * 64 + c) * 8];
      #pragma unroll
      for (int n = 0; n < 4; n++) {
        const int f = n * 16 + kf;
        bf16x8 bfrag;
        if (f < FREG) bfrag = bw[f];
        else bfrag = *(const bf16x8*)&bls[((wave * FLDS + (f - FREG)) * 64 + lane) * 8];
        acc[n] = __builtin_amdgcn_mfma_f32_16x16x32_bf16(a, bfrag, acc[n], 0, 0, 0);
      }
    }
    LGKM_BARRIER();

    // ---- epilogue: pre loads issued here (batched, independent), tanh,
    //      write hs (global) + hsh (LDS) ----
    #pragma unroll
    for (int n = 0; n < 4; n++) {
      #pragma unroll
      for (int q = 0; q < 4; q++) {
        const int bl = lg * 4 + q;
        const int b  = gb0 + bl;
        const int k  = wc0 + n * 16 + lr;
        float s = acc[n][q] + bhv[n]
                + preb[(size_t)q * (T_ * 512) + (size_t)t * 512 + n * 16];
        if (t == 0) s += pimg[(size_t)b * HID + k];
        const float e = __builtin_exp2f(s * 2.885390081777927f);
        const float hv = 1.f - 2.f * __builtin_amdgcn_rcpf(e + 1.f);
        hs[((size_t)b * T_ + t) * HID + k] = (bf16)hv;
        const int c = (k >> 3) ^ (bl & 7);
        hsh[bl * 512 + c * 8 + (k & 7)] = (bf16)hv;
      }
    }
    LGKM_BARRIER();
  }
}

// ---------------------------------------------------------------------------
extern "C" void kernel_launch(void* const* d_in, const int* in_sizes, int n_in,
                              void* d_out, int out_size, void* d_ws, size_t ws_size,
                              hipStream_t stream) {
  const float* img      = (const float*)d_in[0];
  const int*   captions = (const int*)d_in[1];
  const float* embW     = (const float*)d_in[2];
  const float* Wi       = (const float*)d_in[3];
  const float* bi       = (const float*)d_in[4];
  const float* Wx       = (const float*)d_in[5];
  const float* bx       = (const float*)d_in[6];
  const float* Wh       = (const float*)d_in[7];
  const float* bh       = (const float*)d_in[8];
  const float* Wy       = (const float*)d_in[9];
  const float* by       = (const float*)d_in[10];
  float* logits = (float*)d_out;

  // workspace layout (52.8 MB; WhT aliases WxT which is dead after pre-GEMM)
  char* ws = (char*)d_ws;
  bf16*  WyT  = (bf16*)(ws);                   // 32000*512*2 = 32,768,000
  bf16*  WxT  = (bf16*)(ws + 32768000);        //   512*512*2 =    524,288
  bf16*  X    = (bf16*)(ws + 33292288);        //  4096*512*2 =  4,194,304
  bf16*  hs   = (bf16*)(ws + 37486592);        //  4096*512*2 =  4,194,304
  float* pre  = (float*)(ws + 41680896);       //  4032*512*4 =  8,257,536
  float* pimg = (float*)(ws + 49938432);       //   128*512*4 =    262,144
  bf16*  imgB = (bf16*)(ws + 50200576);        //  128*2048*2 =    524,288
  bf16*  WiT  = (bf16*)(ws + 50724864);        //  512*2048*2 =  2,097,152
  bf16*  WhT  = WxT;                           // alias: used only after pre-GEMM

  // 1) weight transposes / converts to bf16
  transpose_w<<<dim3(VOCAB / 64, HID / 64), 256, 0, stream>>>(Wy, WyT, HID, VOCAB);
  transpose_w<<<dim3(HID / 64, EMB / 64), 256, 0, stream>>>(Wx, WxT, EMB, HID);
  transpose_w<<<dim3(HID / 64, IMGF / 64), 256, 0, stream>>>(Wi, WiT, IMGF, HID);
  img_to_bf16<<<128, 256, 0, stream>>>(img, imgB);

  // 2) embedding gather (bf16, padded to 4096 rows)
  embed_gather<<<MPAD, 256, 0, stream>>>(embW, captions, X);

  // 3) pre = X @ Wx + bx   [128^2 kernel; grid M-fast]
  gemm_bt<<<dim3(MPAD / 128, HID / 128), 256, 0, stream>>>(X, WxT, bx, pre, MROWS, HID, HID);

  // 4) pimg = img @ Wi + bi
  gemm_bt<<<dim3(1, HID / 128), 256, 0, stream>>>(imgB, WiT, bi, pimg, B_, HID, IMGF);

  // 5) Wh -> bf16 [col][k] into the (now dead) WxT slot
  transpose_w<<<dim3(HID / 64, HID / 64), 256, 0, stream>>>(Wh, WhT, HID, HID);

  // 6) zero hs pad rows (read by logits GEMM)
  hipMemsetAsync(hs + (size_t)MROWS * HID, 0,
                 (size_t)(MPAD - MROWS) * HID * sizeof(bf16), stream);

  // 7) RNN: all 63 steps, 4 fully-independent blocks (16 batches each)
  rnn_reg8<<<4, 512, 0, stream>>>(pre, WhT, bh, pimg, hs);

  // 8) logits = hs @ Wy + by   [256^2 kernel, 4-buf counted-vmcnt pipeline]
  gemm_bt256<<<dim3(MPAD / 256, VOCAB / 256), 512, 0, stream>>>(hs, WyT, by, logits, MROWS, VOCAB, HID);
}

// Round 11
// 637.928 us; speedup vs baseline: 1.2676x; 1.2676x over previous
//
#include <hip/hip_runtime.h>
#include <hip/hip_bf16.h>

// Problem constants (DecoderRNN): B=64, S=64, IMG_F=2048, EMB=HID=512, VOCAB=32000
#define B_    64
#define S_    64
#define T_    63      // S-1
#define IMGF  2048
#define EMB   512
#define HID   512
#define VOCAB 32000
#define MROWS 4032    // B_*T_
#define MPAD  4096    // padded to multiple of 128

typedef __bf16 bf16;
typedef __bf16 bf16x8 __attribute__((ext_vector_type(8)));
typedef float  f32x4  __attribute__((ext_vector_type(4)));

__device__ __forceinline__ void gload_lds16(const void* g, void* l) {
  __builtin_amdgcn_global_load_lds(
      (const __attribute__((address_space(1))) unsigned int*)g,
      (__attribute__((address_space(3))) unsigned int*)l, 16, 0, 0);
}

// lgkm-only barrier: orders LDS reads/writes across waves WITHOUT draining
// outstanding global (vmcnt) ops.
#define LGKM_BARRIER() asm volatile("s_waitcnt lgkmcnt(0)\n\ts_barrier" ::: "memory")

// ---------------------------------------------------------------------------
// Tiled transpose f32[K][N] -> bf16[N][K]  (64x64 tiles via LDS)
// ---------------------------------------------------------------------------
__global__ __launch_bounds__(256) void transpose_w(
    const float* __restrict__ W, bf16* __restrict__ WT, int K, int N)
{
  __shared__ float tile[64][65];
  const int tx = threadIdx.x & 63, ty = threadIdx.x >> 6;
  const int n0 = blockIdx.x * 64, k0 = blockIdx.y * 64;
  #pragma unroll
  for (int r = ty; r < 64; r += 4)
    tile[r][tx] = W[(size_t)(k0 + r) * N + n0 + tx];
  __syncthreads();
  #pragma unroll
  for (int r = ty; r < 64; r += 4)
    WT[(size_t)(n0 + r) * K + k0 + tx] = (bf16)tile[tx][r];
}

// ---------------------------------------------------------------------------
// Wy transpose into TILED + PRE-SWIZZLED layout for gemm_bt256's B operand.
// Tile (bn, kt) = contiguous 16 KB blob of 1024 16B-chunks; physical chunk
// c = rr*4 + sl holds logical slot (sl ^ ((rr>>1)&3)) of local row rr.
// gemm_bt256 then stages B as a LINEAR lane-contiguous copy (1 KB/instr).
// ---------------------------------------------------------------------------
__global__ __launch_bounds__(256) void transpose_wy_tiled(
    const float* __restrict__ W, bf16* __restrict__ T)   // W: [HID][VOCAB]
{
  __shared__ float tile[64][65];
  const int tx = threadIdx.x & 63, ty = threadIdx.x >> 6;
  const int n0 = blockIdx.x * 64, k0 = blockIdx.y * 64;
  #pragma unroll
  for (int r = ty; r < 64; r += 4)
    tile[r][tx] = W[(size_t)(k0 + r) * VOCAB + n0 + tx];
  __syncthreads();
  #pragma unroll
  for (int r = ty; r < 64; r += 4) {
    const int n = n0 + r, k = k0 + tx;
    const int bn = n >> 8, rr = n & 255, kt = k >> 5;
    const int sl = ((k & 31) >> 3) ^ ((rr >> 1) & 3);
    const size_t dst = (((size_t)(bn * 16 + kt) * 1024 + rr * 4 + sl) << 3)
                     + (k & 7);
    T[dst] = (bf16)tile[tx][r];
  }
}

// ---------------------------------------------------------------------------
// Embedding gather: X[r][e] = embed_W[captions[b, t]][e], r = b*63+t, bf16 out
// ---------------------------------------------------------------------------
__global__ __launch_bounds__(256) void embed_gather(
    const float* __restrict__ embW, const int* __restrict__ captions,
    bf16* __restrict__ X)
{
  const int r = blockIdx.x;
  const int tid = threadIdx.x;
  if (r < MROWS) {
    const int b = r / T_, t = r % T_;            // t in [0,62]
    const int idx = captions[b * S_ + t];
    float2 v = ((const float2*)(embW + (size_t)idx * EMB))[tid];
    X[(size_t)r * EMB + 2 * tid]     = (bf16)v.x;
    X[(size_t)r * EMB + 2 * tid + 1] = (bf16)v.y;
  } else {
    X[(size_t)r * EMB + 2 * tid]     = (bf16)0.f;
    X[(size_t)r * EMB + 2 * tid + 1] = (bf16)0.f;
  }
}

// ---------------------------------------------------------------------------
// img -> bf16, padded to 128 rows
// ---------------------------------------------------------------------------
__global__ __launch_bounds__(256) void img_to_bf16(
    const float* __restrict__ img, bf16* __restrict__ imgB)
{
  const int r = blockIdx.x;          // 0..127
  const int tid = threadIdx.x;
  #pragma unroll
  for (int j = 0; j < 8; j++) {
    const int c = tid + j * 256;     // 0..2047
    const float v = (r < B_) ? img[(size_t)r * IMGF + c] : 0.f;
    imgB[(size_t)r * IMGF + c] = (bf16)v;
  }
}

// ---------------------------------------------------------------------------
// bf16 MFMA GEMM, 128x128 tile, 2-phase (used for the small pre/pimg GEMMs)
// ---------------------------------------------------------------------------
__global__ __launch_bounds__(256) void gemm_bt(
    const bf16* __restrict__ A, const bf16* __restrict__ BT,
    const float* __restrict__ bias, float* __restrict__ C,
    int Mvalid, int N, int K)
{
  __shared__ __align__(16) bf16 As[2][128 * 32];
  __shared__ __align__(16) bf16 Bs[2][128 * 32];
  const int tid  = threadIdx.x;
  const int wave = tid >> 6, lane = tid & 63;
  const int wm = wave >> 1, wn = wave & 1;
  const int bm = blockIdx.x, bn = blockIdx.y;
  const int lg = lane >> 4, lr = lane & 15;

  f32x4 acc[4][4];
  #pragma unroll
  for (int m = 0; m < 4; m++)
    #pragma unroll
    for (int n = 0; n < 4; n++) acc[m][n] = (f32x4){0.f, 0.f, 0.f, 0.f};

  const bf16* Abase = A  + (size_t)bm * 128 * K;
  const bf16* Bbase = BT + (size_t)bn * 128 * K;

  const int c0 = wave * 64 + lane;
  const int r0 = c0 >> 2,  sl0 = (c0 & 3) ^ ((r0 >> 1) & 3);
  const int c1 = 256 + c0;
  const int r1 = c1 >> 2,  sl1 = (c1 & 3) ^ ((r1 >> 1) & 3);

  const int NT = K >> 5;

#define STAGE_TILE(buf, kt)                                                   \
  do {                                                                        \
    gload_lds16(Abase + (size_t)r0 * K + (kt) + sl0 * 8,                      \
                &As[buf][(wave * 64) * 8]);                                   \
    gload_lds16(Abase + (size_t)r1 * K + (kt) + sl1 * 8,                      \
                &As[buf][(256 + wave * 64) * 8]);                             \
    gload_lds16(Bbase + (size_t)r0 * K + (kt) + sl0 * 8,                      \
                &Bs[buf][(wave * 64) * 8]);                                   \
    gload_lds16(Bbase + (size_t)r1 * K + (kt) + sl1 * 8,                      \
                &Bs[buf][(256 + wave * 64) * 8]);                             \
  } while (0)

  STAGE_TILE(0, 0);
  int cur = 0;
  for (int it = 0; it < NT; ++it) {
    __syncthreads();
    if (it + 1 < NT) STAGE_TILE(cur ^ 1, (it + 1) * 32);

    bf16x8 af[4], bfr[4];
    #pragma unroll
    for (int m = 0; m < 4; m++) {
      const int r = wm * 64 + m * 16 + lr;
      const int sp = lg ^ ((r >> 1) & 3);
      af[m] = *(const bf16x8*)&As[cur][r * 32 + sp * 8];
    }
    #pragma unroll
    for (int n = 0; n < 4; n++) {
      const int r = wn * 64 + n * 16 + lr;
      const int sp = lg ^ ((r >> 1) & 3);
      bfr[n] = *(const bf16x8*)&Bs[cur][r * 32 + sp * 8];
    }
    #pragma unroll
    for (int m = 0; m < 4; m++)
      #pragma unroll
      for (int n = 0; n < 4; n++)
        acc[m][n] = __builtin_amdgcn_mfma_f32_16x16x32_bf16(af[m], bfr[n], acc[m][n], 0, 0, 0);
    cur ^= 1;
  }
#undef STAGE_TILE

  const int row0 = bm * 128 + wm * 64 + (lane >> 4) * 4;
  const int col0 = bn * 128 + wn * 64 + lr;
  #pragma unroll
  for (int m = 0; m < 4; m++) {
    #pragma unroll
    for (int n = 0; n < 4; n++) {
      const int col = col0 + n * 16;
      const float bv = bias[col];
      #pragma unroll
      for (int q = 0; q < 4; q++) {
        const int row = row0 + m * 16 + q;
        if (row < Mvalid) C[(size_t)row * N + col] = acc[m][n][q] + bv;
      }
    }
  }
}

// ---------------------------------------------------------------------------
// bf16 MFMA GEMM, 256x256 tile, BK=32, 4-buffer counted-vmcnt pipeline
// (sync structure validated R9/R10). NEW this round:
//  - B operand from TILED pre-swizzled blob -> B stage = linear lane-
//    contiguous copy (64 lanes x 16B = 1 KB/instr, full coalescing)
//  - 1-D grid + XCD-chunk swizzle (2000 = 8 x 250, bijective): each XCD
//    owns complete N-bands -> each B panel pulled by ONE XCD only.
// ---------------------------------------------------------------------------
__global__ __launch_bounds__(512, 1) void gemm_bt256(
    const bf16* __restrict__ A, const bf16* __restrict__ Btile,
    const float* __restrict__ bias, float* __restrict__ C,
    int Mvalid, int N, int K)
{
  __shared__ __align__(16) bf16 sm[4][2][256 * 32];   // [buf][A/B][(r*4+slot)*8]
  const int tid  = threadIdx.x;
  const int wave = tid >> 6, lane = tid & 63;
  const int wm = wave >> 2, wn = wave & 3;
  const int lg = lane >> 4, lr = lane & 15;

  // XCD-chunk swizzle (grid is 1-D, multiple of 8)
  const int id  = blockIdx.x;
  const int cpx = gridDim.x >> 3;               // blocks per XCD chunk
  const int swz = (id & 7) * cpx + (id >> 3);
  const int bm  = swz & 15, bn = swz >> 4;      // M-fast within chunk

  f32x4 acc[8][4];
  #pragma unroll
  for (int m = 0; m < 8; m++)
    #pragma unroll
    for (int n = 0; n < 4; n++) acc[m][n] = (f32x4){0.f, 0.f, 0.f, 0.f};

  const bf16* Abase = A + (size_t)bm * 256 * K;

  // A staging (row-major source): 1024 chunks; 2 per thread, swizzled source
  const int ca0 = tid,        ra0 = ca0 >> 2, sa0 = (ca0 & 3) ^ ((ra0 >> 1) & 3);
  const int ca1 = tid + 512,  ra1 = ca1 >> 2, sa1 = (ca1 & 3) ^ ((ra1 >> 1) & 3);
  const int ldsb0 = (wave * 64) * 8;            // wave-uniform LDS bases
  const int ldsb1 = (512 + wave * 64) * 8;

#define STAGE256(buf, kti)                                                    \
  do {                                                                        \
    const bf16* Bt_ = Btile + (((size_t)bn * 16 + (kti)) << 13);              \
    gload_lds16(Abase + (size_t)ra0 * K + (kti) * 32 + sa0 * 8,               \
                &sm[buf][0][ldsb0]);                                          \
    gload_lds16(Abase + (size_t)ra1 * K + (kti) * 32 + sa1 * 8,               \
                &sm[buf][0][ldsb1]);                                          \
    gload_lds16(Bt_ + (size_t)tid * 8,         &sm[buf][1][ldsb0]);           \
    gload_lds16(Bt_ + (size_t)(tid + 512) * 8, &sm[buf][1][ldsb1]);           \
  } while (0)

  const int NT = K >> 5;                        // 16 for K=512
  STAGE256(0, 0);
  STAGE256(1, 1);
  STAGE256(2, 2);

  #pragma unroll 1
  for (int it = 0; it < NT; ++it) {
    // readiness: my buf[it] loads done (counted), then collective barrier
    const int newer = (NT - 1 - it) > 2 ? 2 : (NT - 1 - it);
    switch (newer) {
      case 2:  asm volatile("s_waitcnt vmcnt(8)\n\ts_barrier" ::: "memory"); break;
      case 1:  asm volatile("s_waitcnt vmcnt(4)\n\ts_barrier" ::: "memory"); break;
      default: asm volatile("s_waitcnt vmcnt(0)\n\ts_barrier" ::: "memory"); break;
    }

    const bf16* As_ = sm[it & 3][0];
    const bf16* Bs_ = sm[it & 3][1];
    bf16x8 af[8], bfr[4];
    #pragma unroll
    for (int m = 0; m < 8; m++) {
      const int r = wm * 128 + m * 16 + lr;
      const int sp = lg ^ ((r >> 1) & 3);
      af[m] = *(const bf16x8*)&As_[(r * 4 + sp) * 8];
    }
    #pragma unroll
    for (int n = 0; n < 4; n++) {
      const int r = wn * 64 + n * 16 + lr;
      const int sp = lg ^ ((r >> 1) & 3);
      bfr[n] = *(const bf16x8*)&Bs_[(r * 4 + sp) * 8];
    }
    #pragma unroll
    for (int m = 0; m < 8; m++)
      #pragma unroll
      for (int n = 0; n < 4; n++)
        acc[m][n] = __builtin_amdgcn_mfma_f32_16x16x32_bf16(af[m], bfr[n], acc[m][n], 0, 0, 0);

    // all waves finished READING buf[it]; safe to overwrite buf[it-1]
    LGKM_BARRIER();
    if (it + 3 < NT) STAGE256((it + 3) & 3, it + 3);
  }
#undef STAGE256

  const int row0 = bm * 256 + wm * 128 + lg * 4;
  const int col0 = bn * 256 + wn * 64 + lr;
  #pragma unroll
  for (int m = 0; m < 8; m++) {
    #pragma unroll
    for (int n = 0; n < 4; n++) {
      const int col = col0 + n * 16;
      const float bv = bias[col];
      #pragma unroll
      for (int q = 0; q < 4; q++) {
        const int row = row0 + m * 16 + q;
        if (row < Mvalid) C[(size_t)row * N + col] = acc[m][n][q] + bv;
      }
    }
  }
}

// ---------------------------------------------------------------------------
// Persistent RNN, 8-wave — EXACT R9 version (FREG=48, FLDS=16, pre prefetch
// at step top). R10's "improvements" regressed it 250 -> 416 µs (VGPR fell
// to 128 with spills); reverted.
// ---------------------------------------------------------------------------
#define FREG 48
#define FLDS 16   // 64 - FREG
__global__ __launch_bounds__(512, 1) void rnn_reg8(
    const float* __restrict__ pre, const bf16* __restrict__ WhT,
    const float* __restrict__ bh, const float* __restrict__ pimg,
    bf16* __restrict__ hs)
{
  const int bg  = blockIdx.x;          // batch group 0..3
  const int tid = threadIdx.x;
  const int wave = tid >> 6, lane = tid & 63;
  const int lg = lane >> 4, lr = lane & 15;
  const int gb0 = bg * 16;             // first batch of block
  const int wc0 = wave * 64;           // first col of wave

  __shared__ __align__(16) bf16 hsh[16 * 512];              // 16 KB
  __shared__ __align__(16) bf16 bls[8 * FLDS * 64 * 8];     // 128 KB

  bf16x8 bw[FREG];
  #pragma unroll
  for (int f = 0; f < 64; f++) {
    const int n = f >> 4, kf = f & 15;
    const bf16x8 v = *(const bf16x8*)(WhT + (size_t)(wc0 + n * 16 + lr) * 512
                                          + kf * 32 + lg * 8);
    if (f < FREG) bw[f] = v;
    else *(bf16x8*)&bls[((wave * FLDS + (f - FREG)) * 64 + lane) * 8] = v;
  }

  *(f32x4*)&hsh[tid * 16]     = (f32x4){0.f, 0.f, 0.f, 0.f};
  *(f32x4*)&hsh[tid * 16 + 8] = (f32x4){0.f, 0.f, 0.f, 0.f};

  float bhv[4];
  #pragma unroll
  for (int n = 0; n < 4; n++) bhv[n] = bh[wc0 + n * 16 + lr];
  const float* preb = pre + ((size_t)(gb0 + lg * 4) * T_) * 512 + wc0 + lr;

  __syncthreads();

  #pragma unroll 1
  for (int t = 0; t < T_; t++) {
    float prq[4][4];
    #pragma unroll
    for (int n = 0; n < 4; n++)
      #pragma unroll
      for (int q = 0; q < 4; q++)
        prq[n][q] = preb[(size_t)q * (T_ * 512) + (size_t)t * 512 + n * 16];

    f32x4 acc[4];
    #pragma unroll
    for (int n = 0; n < 4; n++) acc[n] = (f32x4){0.f, 0.f, 0.f, 0.f};

    #pragma unroll
    for (int kf = 0; kf < 16; kf++) {
      const int c = (kf * 4 + lg) ^ (lr & 7);
      const bf16x8 a = *(const bf16x8*)&hsh[(lr * 64 + c) * 8];
      #pragma unroll
      for (int n = 0; n < 4; n++) {
        const int f = n * 16 + kf;
        bf16x8 bfrag;
        if (f < FREG) bfrag = bw[f];
        else bfrag = *(const bf16x8*)&bls[((wave * FLDS + (f - FREG)) * 64 + lane) * 8];
        acc[n] = __builtin_amdgcn_mfma_f32_16x16x32_bf16(a, bfrag, acc[n], 0, 0, 0);
      }
    }
    LGKM_BARRIER();

    #pragma unroll
    for (int n = 0; n < 4; n++) {
      #pragma unroll
      for (int q = 0; q < 4; q++) {
        const int bl = lg * 4 + q;
        const int b  = gb0 + bl;
        const int k  = wc0 + n * 16 + lr;
        float s = acc[n][q] + prq[n][q] + bhv[n];
        if (t == 0) s += pimg[(size_t)b * HID + k];
        const float e = __builtin_exp2f(s * 2.885390081777927f);
        const float hv = 1.f - 2.f * __builtin_amdgcn_rcpf(e + 1.f);
        hs[((size_t)b * T_ + t) * HID + k] = (bf16)hv;
        const int c = (k >> 3) ^ (bl & 7);
        hsh[bl * 512 + c * 8 + (k & 7)] = (bf16)hv;
      }
    }
    LGKM_BARRIER();
  }
}

// ---------------------------------------------------------------------------
extern "C" void kernel_launch(void* const* d_in, const int* in_sizes, int n_in,
                              void* d_out, int out_size, void* d_ws, size_t ws_size,
                              hipStream_t stream) {
  const float* img      = (const float*)d_in[0];
  const int*   captions = (const int*)d_in[1];
  const float* embW     = (const float*)d_in[2];
  const float* Wi       = (const float*)d_in[3];
  const float* bi       = (const float*)d_in[4];
  const float* Wx       = (const float*)d_in[5];
  const float* bx       = (const float*)d_in[6];
  const float* Wh       = (const float*)d_in[7];
  const float* bh       = (const float*)d_in[8];
  const float* Wy       = (const float*)d_in[9];
  const float* by       = (const float*)d_in[10];
  float* logits = (float*)d_out;

  // workspace layout (52.8 MB; WhT aliases WxT which is dead after pre-GEMM)
  char* ws = (char*)d_ws;
  bf16*  WyT  = (bf16*)(ws);                   // tiled blob, 32,768,000 B
  bf16*  WxT  = (bf16*)(ws + 32768000);        //   512*512*2 =    524,288
  bf16*  X    = (bf16*)(ws + 33292288);        //  4096*512*2 =  4,194,304
  bf16*  hs   = (bf16*)(ws + 37486592);        //  4096*512*2 =  4,194,304
  float* pre  = (float*)(ws + 41680896);       //  4032*512*4 =  8,257,536
  float* pimg = (float*)(ws + 49938432);       //   128*512*4 =    262,144
  bf16*  imgB = (bf16*)(ws + 50200576);        //  128*2048*2 =    524,288
  bf16*  WiT  = (bf16*)(ws + 50724864);        //  512*2048*2 =  2,097,152
  bf16*  WhT  = WxT;                           // alias: used only after pre-GEMM

  // 1) weight transposes / converts to bf16 (Wy -> tiled pre-swizzled blob)
  transpose_wy_tiled<<<dim3(VOCAB / 64, HID / 64), 256, 0, stream>>>(Wy, WyT);
  transpose_w<<<dim3(HID / 64, EMB / 64), 256, 0, stream>>>(Wx, WxT, EMB, HID);
  transpose_w<<<dim3(HID / 64, IMGF / 64), 256, 0, stream>>>(Wi, WiT, IMGF, HID);
  img_to_bf16<<<128, 256, 0, stream>>>(img, imgB);

  // 2) embedding gather (bf16, padded to 4096 rows)
  embed_gather<<<MPAD, 256, 0, stream>>>(embW, captions, X);

  // 3) pre = X @ Wx + bx   [128^2 kernel; grid M-fast]
  gemm_bt<<<dim3(MPAD / 128, HID / 128), 256, 0, stream>>>(X, WxT, bx, pre, MROWS, HID, HID);

  // 4) pimg = img @ Wi + bi
  gemm_bt<<<dim3(1, HID / 128), 256, 0, stream>>>(imgB, WiT, bi, pimg, B_, HID, IMGF);

  // 5) Wh -> bf16 [col][k] into the (now dead) WxT slot
  transpose_w<<<dim3(HID / 64, HID / 64), 256, 0, stream>>>(Wh, WhT, HID, HID);

  // 6) zero hs pad rows (read by logits GEMM)
  hipMemsetAsync(hs + (size_t)MROWS * HID, 0,
                 (size_t)(MPAD - MROWS) * HID * sizeof(bf16), stream);

  // 7) RNN: all 63 steps, 4 fully-independent blocks (16 batches each)
  rnn_reg8<<<4, 512, 0, stream>>>(pre, WhT, bh, pimg, hs);

  // 8) logits = hs @ Wy + by   [256^2, tiled-B, XCD-chunked 1-D grid]
  gemm_bt256<<<(MPAD / 256) * (VOCAB / 256), 512, 0, stream>>>(
      hs, WyT, by, logits, MROWS, VOCAB, HID);
}

// Round 12
// 587.822 us; speedup vs baseline: 1.3757x; 1.0852x over previous
//
#include <hip/hip_runtime.h>
#include <hip/hip_bf16.h>

// Problem constants (DecoderRNN): B=64, S=64, IMG_F=2048, EMB=HID=512, VOCAB=32000
#define B_    64
#define S_    64
#define T_    63      // S-1
#define IMGF  2048
#define EMB   512
#define HID   512
#define VOCAB 32000
#define MROWS 4032    // B_*T_
#define MPAD  4096    // padded to multiple of 128

typedef __bf16 bf16;
typedef __bf16 bf16x8 __attribute__((ext_vector_type(8)));
typedef float  f32x4  __attribute__((ext_vector_type(4)));

__device__ __forceinline__ void gload_lds16(const void* g, void* l) {
  __builtin_amdgcn_global_load_lds(
      (const __attribute__((address_space(1))) unsigned int*)g,
      (__attribute__((address_space(3))) unsigned int*)l, 16, 0, 0);
}

// lgkm-only barrier: orders LDS reads/writes across waves WITHOUT draining
// outstanding global (vmcnt) ops.
#define LGKM_BARRIER() asm volatile("s_waitcnt lgkmcnt(0)\n\ts_barrier" ::: "memory")

// ---------------------------------------------------------------------------
// Tiled transpose f32[K][N] -> bf16[N][K]  (64x64 tiles via LDS)
// ---------------------------------------------------------------------------
__global__ __launch_bounds__(256) void transpose_w(
    const float* __restrict__ W, bf16* __restrict__ WT, int K, int N)
{
  __shared__ float tile[64][65];
  const int tx = threadIdx.x & 63, ty = threadIdx.x >> 6;
  const int n0 = blockIdx.x * 64, k0 = blockIdx.y * 64;
  #pragma unroll
  for (int r = ty; r < 64; r += 4)
    tile[r][tx] = W[(size_t)(k0 + r) * N + n0 + tx];
  __syncthreads();
  #pragma unroll
  for (int r = ty; r < 64; r += 4)
    WT[(size_t)(n0 + r) * K + k0 + tx] = (bf16)tile[tx][r];
}

// ---------------------------------------------------------------------------
// Wy transpose into TILED + PRE-SWIZZLED layout for gemm_bt256's B operand.
// ---------------------------------------------------------------------------
__global__ __launch_bounds__(256) void transpose_wy_tiled(
    const float* __restrict__ W, bf16* __restrict__ T)   // W: [HID][VOCAB]
{
  __shared__ float tile[64][65];
  const int tx = threadIdx.x & 63, ty = threadIdx.x >> 6;
  const int n0 = blockIdx.x * 64, k0 = blockIdx.y * 64;
  #pragma unroll
  for (int r = ty; r < 64; r += 4)
    tile[r][tx] = W[(size_t)(k0 + r) * VOCAB + n0 + tx];
  __syncthreads();
  #pragma unroll
  for (int r = ty; r < 64; r += 4) {
    const int n = n0 + r, k = k0 + tx;
    const int bn = n >> 8, rr = n & 255, kt = k >> 5;
    const int sl = ((k & 31) >> 3) ^ ((rr >> 1) & 3);
    const size_t dst = (((size_t)(bn * 16 + kt) * 1024 + rr * 4 + sl) << 3)
                     + (k & 7);
    T[dst] = (bf16)tile[tx][r];
  }
}

// ---------------------------------------------------------------------------
// Embedding gather: X[r][e] = embed_W[captions[b, t]][e], r = b*63+t, bf16 out
// ---------------------------------------------------------------------------
__global__ __launch_bounds__(256) void embed_gather(
    const float* __restrict__ embW, const int* __restrict__ captions,
    bf16* __restrict__ X)
{
  const int r = blockIdx.x;
  const int tid = threadIdx.x;
  if (r < MROWS) {
    const int b = r / T_, t = r % T_;            // t in [0,62]
    const int idx = captions[b * S_ + t];
    float2 v = ((const float2*)(embW + (size_t)idx * EMB))[tid];
    X[(size_t)r * EMB + 2 * tid]     = (bf16)v.x;
    X[(size_t)r * EMB + 2 * tid + 1] = (bf16)v.y;
  } else {
    X[(size_t)r * EMB + 2 * tid]     = (bf16)0.f;
    X[(size_t)r * EMB + 2 * tid + 1] = (bf16)0.f;
  }
}

// ---------------------------------------------------------------------------
// img -> bf16, padded to 128 rows
// ---------------------------------------------------------------------------
__global__ __launch_bounds__(256) void img_to_bf16(
    const float* __restrict__ img, bf16* __restrict__ imgB)
{
  const int r = blockIdx.x;          // 0..127
  const int tid = threadIdx.x;
  #pragma unroll
  for (int j = 0; j < 8; j++) {
    const int c = tid + j * 256;     // 0..2047
    const float v = (r < B_) ? img[(size_t)r * IMGF + c] : 0.f;
    imgB[(size_t)r * IMGF + c] = (bf16)v;
  }
}

// ---------------------------------------------------------------------------
// bf16 MFMA GEMM, 128x128 tile, 2-phase (used for the small pre/pimg GEMMs)
// ---------------------------------------------------------------------------
__global__ __launch_bounds__(256) void gemm_bt(
    const bf16* __restrict__ A, const bf16* __restrict__ BT,
    const float* __restrict__ bias, float* __restrict__ C,
    int Mvalid, int N, int K)
{
  __shared__ __align__(16) bf16 As[2][128 * 32];
  __shared__ __align__(16) bf16 Bs[2][128 * 32];
  const int tid  = threadIdx.x;
  const int wave = tid >> 6, lane = tid & 63;
  const int wm = wave >> 1, wn = wave & 1;
  const int bm = blockIdx.x, bn = blockIdx.y;
  const int lg = lane >> 4, lr = lane & 15;

  f32x4 acc[4][4];
  #pragma unroll
  for (int m = 0; m < 4; m++)
    #pragma unroll
    for (int n = 0; n < 4; n++) acc[m][n] = (f32x4){0.f, 0.f, 0.f, 0.f};

  const bf16* Abase = A  + (size_t)bm * 128 * K;
  const bf16* Bbase = BT + (size_t)bn * 128 * K;

  const int c0 = wave * 64 + lane;
  const int r0 = c0 >> 2,  sl0 = (c0 & 3) ^ ((r0 >> 1) & 3);
  const int c1 = 256 + c0;
  const int r1 = c1 >> 2,  sl1 = (c1 & 3) ^ ((r1 >> 1) & 3);

  const int NT = K >> 5;

#define STAGE_TILE(buf, kt)                                                   \
  do {                                                                        \
    gload_lds16(Abase + (size_t)r0 * K + (kt) + sl0 * 8,                      \
                &As[buf][(wave * 64) * 8]);                                   \
    gload_lds16(Abase + (size_t)r1 * K + (kt) + sl1 * 8,                      \
                &As[buf][(256 + wave * 64) * 8]);                             \
    gload_lds16(Bbase + (size_t)r0 * K + (kt) + sl0 * 8,                      \
                &Bs[buf][(wave * 64) * 8]);                                   \
    gload_lds16(Bbase + (size_t)r1 * K + (kt) + sl1 * 8,                      \
                &Bs[buf][(256 + wave * 64) * 8]);                             \
  } while (0)

  STAGE_TILE(0, 0);
  int cur = 0;
  for (int it = 0; it < NT; ++it) {
    __syncthreads();
    if (it + 1 < NT) STAGE_TILE(cur ^ 1, (it + 1) * 32);

    bf16x8 af[4], bfr[4];
    #pragma unroll
    for (int m = 0; m < 4; m++) {
      const int r = wm * 64 + m * 16 + lr;
      const int sp = lg ^ ((r >> 1) & 3);
      af[m] = *(const bf16x8*)&As[cur][r * 32 + sp * 8];
    }
    #pragma unroll
    for (int n = 0; n < 4; n++) {
      const int r = wn * 64 + n * 16 + lr;
      const int sp = lg ^ ((r >> 1) & 3);
      bfr[n] = *(const bf16x8*)&Bs[cur][r * 32 + sp * 8];
    }
    #pragma unroll
    for (int m = 0; m < 4; m++)
      #pragma unroll
      for (int n = 0; n < 4; n++)
        acc[m][n] = __builtin_amdgcn_mfma_f32_16x16x32_bf16(af[m], bfr[n], acc[m][n], 0, 0, 0);
    cur ^= 1;
  }
#undef STAGE_TILE

  const int row0 = bm * 128 + wm * 64 + (lane >> 4) * 4;
  const int col0 = bn * 128 + wn * 64 + lr;
  #pragma unroll
  for (int m = 0; m < 4; m++) {
    #pragma unroll
    for (int n = 0; n < 4; n++) {
      const int col = col0 + n * 16;
      const float bv = bias[col];
      #pragma unroll
      for (int q = 0; q < 4; q++) {
        const int row = row0 + m * 16 + q;
        if (row < Mvalid) C[(size_t)row * N + col] = acc[m][n][q] + bv;
      }
    }
  }
}

// ---------------------------------------------------------------------------
// bf16 MFMA GEMM, 256x256 tile, BK=32, 4-buffer counted-vmcnt pipeline
// (sync structure validated R9-R11; tiled-B + XCD swizzle kept from R11).
// NEW: LDS-STAGED EPILOGUE — after the K-loop, sm (128 KB) is reused as an
// f32 staging tile. Two 128-row passes: the wm-half that owns the rows
// writes acc+bias into cst[r][c] (stride 256), barrier, then ALL 8 waves
// store complete rows with global_store_dwordx4 (64 lanes x 16B = 1 KB
// contiguous per instruction; 32 stores/thread instead of 128 scalar 4B).
// Tests the theory that the 64B-segment scalar-store epilogue is what holds
// every GEMM variant at ~300 µs.
// ---------------------------------------------------------------------------
__global__ __launch_bounds__(512, 1) void gemm_bt256(
    const bf16* __restrict__ A, const bf16* __restrict__ Btile,
    const float* __restrict__ bias, float* __restrict__ C,
    int Mvalid, int N, int K)
{
  __shared__ __align__(16) bf16 sm[4][2][256 * 32];   // [buf][A/B][(r*4+slot)*8]
  const int tid  = threadIdx.x;
  const int wave = tid >> 6, lane = tid & 63;
  const int wm = wave >> 2, wn = wave & 3;
  const int lg = lane >> 4, lr = lane & 15;

  // XCD-chunk swizzle (grid is 1-D, multiple of 8)
  const int id  = blockIdx.x;
  const int cpx = gridDim.x >> 3;               // blocks per XCD chunk
  const int swz = (id & 7) * cpx + (id >> 3);
  const int bm  = swz & 15, bn = swz >> 4;      // M-fast within chunk

  f32x4 acc[8][4];
  #pragma unroll
  for (int m = 0; m < 8; m++)
    #pragma unroll
    for (int n = 0; n < 4; n++) acc[m][n] = (f32x4){0.f, 0.f, 0.f, 0.f};

  const bf16* Abase = A + (size_t)bm * 256 * K;

  // A staging (row-major source): 1024 chunks; 2 per thread, swizzled source
  const int ca0 = tid,        ra0 = ca0 >> 2, sa0 = (ca0 & 3) ^ ((ra0 >> 1) & 3);
  const int ca1 = tid + 512,  ra1 = ca1 >> 2, sa1 = (ca1 & 3) ^ ((ra1 >> 1) & 3);
  const int ldsb0 = (wave * 64) * 8;            // wave-uniform LDS bases
  const int ldsb1 = (512 + wave * 64) * 8;

#define STAGE256(buf, kti)                                                    \
  do {                                                                        \
    const bf16* Bt_ = Btile + (((size_t)bn * 16 + (kti)) << 13);              \
    gload_lds16(Abase + (size_t)ra0 * K + (kti) * 32 + sa0 * 8,               \
                &sm[buf][0][ldsb0]);                                          \
    gload_lds16(Abase + (size_t)ra1 * K + (kti) * 32 + sa1 * 8,               \
                &sm[buf][0][ldsb1]);                                          \
    gload_lds16(Bt_ + (size_t)tid * 8,         &sm[buf][1][ldsb0]);           \
    gload_lds16(Bt_ + (size_t)(tid + 512) * 8, &sm[buf][1][ldsb1]);           \
  } while (0)

  const int NT = K >> 5;                        // 16 for K=512
  STAGE256(0, 0);
  STAGE256(1, 1);
  STAGE256(2, 2);

  #pragma unroll 1
  for (int it = 0; it < NT; ++it) {
    // readiness: my buf[it] loads done (counted), then collective barrier
    const int newer = (NT - 1 - it) > 2 ? 2 : (NT - 1 - it);
    switch (newer) {
      case 2:  asm volatile("s_waitcnt vmcnt(8)\n\ts_barrier" ::: "memory"); break;
      case 1:  asm volatile("s_waitcnt vmcnt(4)\n\ts_barrier" ::: "memory"); break;
      default: asm volatile("s_waitcnt vmcnt(0)\n\ts_barrier" ::: "memory"); break;
    }

    const bf16* As_ = sm[it & 3][0];
    const bf16* Bs_ = sm[it & 3][1];
    bf16x8 af[8], bfr[4];
    #pragma unroll
    for (int m = 0; m < 8; m++) {
      const int r = wm * 128 + m * 16 + lr;
      const int sp = lg ^ ((r >> 1) & 3);
      af[m] = *(const bf16x8*)&As_[(r * 4 + sp) * 8];
    }
    #pragma unroll
    for (int n = 0; n < 4; n++) {
      const int r = wn * 64 + n * 16 + lr;
      const int sp = lg ^ ((r >> 1) & 3);
      bfr[n] = *(const bf16x8*)&Bs_[(r * 4 + sp) * 8];
    }
    #pragma unroll
    for (int m = 0; m < 8; m++)
      #pragma unroll
      for (int n = 0; n < 4; n++)
        acc[m][n] = __builtin_amdgcn_mfma_f32_16x16x32_bf16(af[m], bfr[n], acc[m][n], 0, 0, 0);

    // all waves finished READING buf[it]; safe to overwrite buf[it-1]
    LGKM_BARRIER();
    if (it + 3 < NT) STAGE256((it + 3) & 3, it + 3);
  }
#undef STAGE256

  // ---- LDS-staged epilogue: coalesced dwordx4 C stores ----
  float* cst = (float*)&sm[0][0][0];            // 128 KB = 128 rows x 256 f32
  float bvv[4];
  #pragma unroll
  for (int n = 0; n < 4; n++)
    bvv[n] = bias[bn * 256 + wn * 64 + n * 16 + lr];

  #pragma unroll
  for (int pass = 0; pass < 2; ++pass) {
    if (wm == pass) {                           // owners of these 128 rows
      #pragma unroll
      for (int m = 0; m < 8; m++)
        #pragma unroll
        for (int n = 0; n < 4; n++) {
          const int cc = wn * 64 + n * 16 + lr;
          #pragma unroll
          for (int q = 0; q < 4; q++)
            cst[(m * 16 + lg * 4 + q) * 256 + cc] = acc[m][n][q] + bvv[n];
        }
    }
    __syncthreads();
    const int rbase = bm * 256 + pass * 128;
    #pragma unroll
    for (int i = 0; i < 16; i++) {
      const int r = i * 8 + wave;               // 0..127
      const int grow = rbase + r;
      if (grow < Mvalid) {
        const f32x4 v = *(const f32x4*)&cst[r * 256 + lane * 4];
        *(f32x4*)&C[(size_t)grow * N + bn * 256 + lane * 4] = v;
      }
    }
    __syncthreads();                            // before pass 1 overwrites
  }
}

// ---------------------------------------------------------------------------
// Persistent RNN, 8-wave — EXACT R9/R11 version (unchanged this round).
// ---------------------------------------------------------------------------
#define FREG 48
#define FLDS 16   // 64 - FREG
__global__ __launch_bounds__(512, 1) void rnn_reg8(
    const float* __restrict__ pre, const bf16* __restrict__ WhT,
    const float* __restrict__ bh, const float* __restrict__ pimg,
    bf16* __restrict__ hs)
{
  const int bg  = blockIdx.x;          // batch group 0..3
  const int tid = threadIdx.x;
  const int wave = tid >> 6, lane = tid & 63;
  const int lg = lane >> 4, lr = lane & 15;
  const int gb0 = bg * 16;             // first batch of block
  const int wc0 = wave * 64;           // first col of wave

  __shared__ __align__(16) bf16 hsh[16 * 512];              // 16 KB
  __shared__ __align__(16) bf16 bls[8 * FLDS * 64 * 8];     // 128 KB

  bf16x8 bw[FREG];
  #pragma unroll
  for (int f = 0; f < 64; f++) {
    const int n = f >> 4, kf = f & 15;
    const bf16x8 v = *(const bf16x8*)(WhT + (size_t)(wc0 + n * 16 + lr) * 512
                                          + kf * 32 + lg * 8);
    if (f < FREG) bw[f] = v;
    else *(bf16x8*)&bls[((wave * FLDS + (f - FREG)) * 64 + lane) * 8] = v;
  }

  *(f32x4*)&hsh[tid * 16]     = (f32x4){0.f, 0.f, 0.f, 0.f};
  *(f32x4*)&hsh[tid * 16 + 8] = (f32x4){0.f, 0.f, 0.f, 0.f};

  float bhv[4];
  #pragma unroll
  for (int n = 0; n < 4; n++) bhv[n] = bh[wc0 + n * 16 + lr];
  const float* preb = pre + ((size_t)(gb0 + lg * 4) * T_) * 512 + wc0 + lr;

  __syncthreads();

  #pragma unroll 1
  for (int t = 0; t < T_; t++) {
    float prq[4][4];
    #pragma unroll
    for (int n = 0; n < 4; n++)
      #pragma unroll
      for (int q = 0; q < 4; q++)
        prq[n][q] = preb[(size_t)q * (T_ * 512) + (size_t)t * 512 + n * 16];

    f32x4 acc[4];
    #pragma unroll
    for (int n = 0; n < 4; n++) acc[n] = (f32x4){0.f, 0.f, 0.f, 0.f};

    #pragma unroll
    for (int kf = 0; kf < 16; kf++) {
      const int c = (kf * 4 + lg) ^ (lr & 7);
      const bf16x8 a = *(const bf16x8*)&hsh[(lr * 64 + c) * 8];
      #pragma unroll
      for (int n = 0; n < 4; n++) {
        const int f = n * 16 + kf;
        bf16x8 bfrag;
        if (f < FREG) bfrag = bw[f];
        else bfrag = *(const bf16x8*)&bls[((wave * FLDS + (f - FREG)) * 64 + lane) * 8];
        acc[n] = __builtin_amdgcn_mfma_f32_16x16x32_bf16(a, bfrag, acc[n], 0, 0, 0);
      }
    }
    LGKM_BARRIER();

    #pragma unroll
    for (int n = 0; n < 4; n++) {
      #pragma unroll
      for (int q = 0; q < 4; q++) {
        const int bl = lg * 4 + q;
        const int b  = gb0 + bl;
        const int k  = wc0 + n * 16 + lr;
        float s = acc[n][q] + prq[n][q] + bhv[n];
        if (t == 0) s += pimg[(size_t)b * HID + k];
        const float e = __builtin_exp2f(s * 2.885390081777927f);
        const float hv = 1.f - 2.f * __builtin_amdgcn_rcpf(e + 1.f);
        hs[((size_t)b * T_ + t) * HID + k] = (bf16)hv;
        const int c = (k >> 3) ^ (bl & 7);
        hsh[bl * 512 + c * 8 + (k & 7)] = (bf16)hv;
      }
    }
    LGKM_BARRIER();
  }
}

// ---------------------------------------------------------------------------
extern "C" void kernel_launch(void* const* d_in, const int* in_sizes, int n_in,
                              void* d_out, int out_size, void* d_ws, size_t ws_size,
                              hipStream_t stream) {
  const float* img      = (const float*)d_in[0];
  const int*   captions = (const int*)d_in[1];
  const float* embW     = (const float*)d_in[2];
  const float* Wi       = (const float*)d_in[3];
  const float* bi       = (const float*)d_in[4];
  const float* Wx       = (const float*)d_in[5];
  const float* bx       = (const float*)d_in[6];
  const float* Wh       = (const float*)d_in[7];
  const float* bh       = (const float*)d_in[8];
  const float* Wy       = (const float*)d_in[9];
  const float* by       = (const float*)d_in[10];
  float* logits = (float*)d_out;

  // workspace layout (52.8 MB; WhT aliases WxT which is dead after pre-GEMM)
  char* ws = (char*)d_ws;
  bf16*  WyT  = (bf16*)(ws);                   // tiled blob, 32,768,000 B
  bf16*  WxT  = (bf16*)(ws + 32768000);        //   512*512*2 =    524,288
  bf16*  X    = (bf16*)(ws + 33292288);        //  4096*512*2 =  4,194,304
  bf16*  hs   = (bf16*)(ws + 37486592);        //  4096*512*2 =  4,194,304
  float* pre  = (float*)(ws + 41680896);       //  4032*512*4 =  8,257,536
  float* pimg = (float*)(ws + 49938432);       //   128*512*4 =    262,144
  bf16*  imgB = (bf16*)(ws + 50200576);        //  128*2048*2 =    524,288
  bf16*  WiT  = (bf16*)(ws + 50724864);        //  512*2048*2 =  2,097,152
  bf16*  WhT  = WxT;                           // alias: used only after pre-GEMM

  // 1) weight transposes / converts to bf16 (Wy -> tiled pre-swizzled blob)
  transpose_wy_tiled<<<dim3(VOCAB / 64, HID / 64), 256, 0, stream>>>(Wy, WyT);
  transpose_w<<<dim3(HID / 64, EMB / 64), 256, 0, stream>>>(Wx, WxT, EMB, HID);
  transpose_w<<<dim3(HID / 64, IMGF / 64), 256, 0, stream>>>(Wi, WiT, IMGF, HID);
  img_to_bf16<<<128, 256, 0, stream>>>(img, imgB);

  // 2) embedding gather (bf16, padded to 4096 rows)
  embed_gather<<<MPAD, 256, 0, stream>>>(embW, captions, X);

  // 3) pre = X @ Wx + bx   [128^2 kernel; grid M-fast]
  gemm_bt<<<dim3(MPAD / 128, HID / 128), 256, 0, stream>>>(X, WxT, bx, pre, MROWS, HID, HID);

  // 4) pimg = img @ Wi + bi
  gemm_bt<<<dim3(1, HID / 128), 256, 0, stream>>>(imgB, WiT, bi, pimg, B_, HID, IMGF);

  // 5) Wh -> bf16 [col][k] into the (now dead) WxT slot
  transpose_w<<<dim3(HID / 64, HID / 64), 256, 0, stream>>>(Wh, WhT, HID, HID);

  // 6) zero hs pad rows (read by logits GEMM)
  hipMemsetAsync(hs + (size_t)MROWS * HID, 0,
                 (size_t)(MPAD - MROWS) * HID * sizeof(bf16), stream);

  // 7) RNN: all 63 steps, 4 fully-independent blocks (16 batches each)
  rnn_reg8<<<4, 512, 0, stream>>>(pre, WhT, bh, pimg, hs);

  // 8) logits = hs @ Wy + by   [256^2, tiled-B, XCD-chunked, LDS epilogue]
  gemm_bt256<<<(MPAD / 256) * (VOCAB / 256), 512, 0, stream>>>(
      hs, WyT, by, logits, MROWS, VOCAB, HID);
}